// Round 1
// baseline (3690.574 us; speedup 1.0000x reference)
//
#include <hip/hip_runtime.h>

#define T_TOK 4096
#define DDIM 2048
#define FDIM 4096
#define NEXP 8
#define ALPHA_C 1.702f
#define FLIMIT 7.0f
#define BM 128
#define BN 128
#define BK 32

typedef __attribute__((ext_vector_type(8))) short s16x8;   // 8 bf16 (4 VGPRs)
typedef __attribute__((ext_vector_type(4))) float f32x4;
typedef __attribute__((ext_vector_type(4))) unsigned int u32x4;

// fp32 -> bf16 bits, round-to-nearest-even (inputs are finite; no NaN path)
__device__ __forceinline__ short f2bf(float f) {
  unsigned int u = __float_as_uint(f);
  u += 0x7fffu + ((u >> 16) & 1u);
  return (short)(unsigned short)(u >> 16);
}

// ---------------- router: logits, top-2, expert lists, x -> bf16 ----------------
__global__ __launch_bounds__(256) void router_kernel(
    const float* __restrict__ x, const float* __restrict__ rw,
    const float* __restrict__ rb, short* __restrict__ xb,
    int* __restrict__ counts, int* __restrict__ toklist,
    float* __restrict__ wlist) {
  const int t = (int)((blockIdx.x * 256 + threadIdx.x) >> 6);  // one wave per token
  const int lane = threadIdx.x & 63;
  const float* xr = x + (size_t)t * DDIM;
  float acc[NEXP];
#pragma unroll
  for (int e = 0; e < NEXP; ++e) acc[e] = 0.f;
  for (int j = 0; j < DDIM / 64; ++j) {
    const int idx = j * 64 + lane;
    const float xv = xr[idx];
    xb[(size_t)t * DDIM + idx] = f2bf(xv);
#pragma unroll
    for (int e = 0; e < NEXP; ++e) acc[e] += xv * rw[e * DDIM + idx];
  }
#pragma unroll
  for (int e = 0; e < NEXP; ++e) {
#pragma unroll
    for (int off = 32; off > 0; off >>= 1) acc[e] += __shfl_down(acc[e], off, 64);
  }
  if (lane == 0) {
    float l0 = -1e30f;
    int e0 = 0;
#pragma unroll
    for (int e = 0; e < NEXP; ++e) {
      acc[e] += rb[e];
      if (acc[e] > l0) { l0 = acc[e]; e0 = e; }
    }
    float l1 = -1e30f;
    int e1 = 0;
#pragma unroll
    for (int e = 0; e < NEXP; ++e) {
      if (e != e0 && acc[e] > l1) { l1 = acc[e]; e1 = e; }
    }
    // renormalized top-2 softmax weights
    const float wA = 1.f / (1.f + __expf(l1 - l0));
    const float wB = 1.f - wA;
    const int s0 = atomicAdd(&counts[e0], 1);
    toklist[e0 * T_TOK + s0] = t * 2;
    wlist[e0 * T_TOK + s0] = wA;
    const int s1 = atomicAdd(&counts[e1], 1);
    toklist[e1 * T_TOK + s1] = t * 2 + 1;
    wlist[e1 * T_TOK + s1] = wB;
  }
}

// ---------------- GEMM1: h = swiglu(Xg@w1+b1, Xg@w3+b3), gathered rows ----------------
__global__ __launch_bounds__(256, 2) void gemm1_kernel(
    const short* __restrict__ xb, const float* __restrict__ w1g,
    const float* __restrict__ b1g, const float* __restrict__ w3g,
    const float* __restrict__ b3g, const int* __restrict__ counts,
    const int* __restrict__ toklist, short* __restrict__ h) {
  const int e = blockIdx.z;
  const int n_e = counts[e];
  const int m0 = blockIdx.x * BM;
  if (m0 >= n_e) return;
  const int n0 = blockIdx.y * BN;
  const float* w1 = w1g + (size_t)e * DDIM * FDIM;
  const float* w3 = w3g + (size_t)e * DDIM * FDIM;

  __shared__ short Alds[BM * BK];
  __shared__ short B1lds[BN * BK];  // stored [n][k]
  __shared__ short B3lds[BN * BK];
  __shared__ int rowtok[BM];

  const int tid = threadIdx.x;
  if (tid < BM) {
    int r = m0 + tid;
    if (r >= n_e) r = n_e - 1;  // clamp; stores masked in epilogue
    rowtok[tid] = toklist[e * T_TOK + r];
  }
  __syncthreads();

  const int arow0 = tid >> 2;
  const int achk = tid & 3;
  const short* aptr0 = xb + (size_t)(rowtok[arow0] >> 1) * DDIM + achk * 8;
  const short* aptr1 = xb + (size_t)(rowtok[arow0 + 64] >> 1) * DDIM + achk * 8;

  const int bn = tid & 127;
  const int bkh = (tid >> 7) * 8;

  const int wave = tid >> 6;
  const int lane = tid & 63;
  const int wm = (wave >> 1) * 64;
  const int wn = (wave & 1) * 64;
  const int lr = lane & 15;
  const int lq = lane >> 4;

  f32x4 accg[4][4], accu[4][4];
  const f32x4 zero = {0.f, 0.f, 0.f, 0.f};
#pragma unroll
  for (int i = 0; i < 4; ++i)
#pragma unroll
    for (int j = 0; j < 4; ++j) { accg[i][j] = zero; accu[i][j] = zero; }

  for (int kt = 0; kt < DDIM / BK; ++kt) {
    __syncthreads();
    // stage A (gathered bf16 rows)
    {
      u32x4 va0 = *(const u32x4*)(aptr0 + kt * BK);
      u32x4 va1 = *(const u32x4*)(aptr1 + kt * BK);
      *(u32x4*)&Alds[arow0 * BK + achk * 8] = va0;
      *(u32x4*)&Alds[(arow0 + 64) * BK + achk * 8] = va1;
    }
    // stage B1/B3: fp32 global, convert to bf16, store transposed [n][k]
#pragma unroll
    for (int c = 0; c < 2; ++c) {
      const int k0 = bkh + c * 16;
      const float* s1 = w1 + (size_t)(kt * BK + k0) * FDIM + (n0 + bn);
      const float* s3 = w3 + (size_t)(kt * BK + k0) * FDIM + (n0 + bn);
      s16x8 v1, v3;
#pragma unroll
      for (int j = 0; j < 8; ++j) {
        v1[j] = f2bf(s1[(size_t)j * FDIM]);
        v3[j] = f2bf(s3[(size_t)j * FDIM]);
      }
      *(s16x8*)&B1lds[bn * BK + k0] = v1;
      *(s16x8*)&B3lds[bn * BK + k0] = v3;
    }
    __syncthreads();
    // compute
    s16x8 af[4];
#pragma unroll
    for (int mf = 0; mf < 4; ++mf)
      af[mf] = *(const s16x8*)&Alds[(wm + mf * 16 + lr) * BK + lq * 8];
#pragma unroll
    for (int nf = 0; nf < 4; ++nf) {
      s16x8 bg = *(const s16x8*)&B1lds[(wn + nf * 16 + lr) * BK + lq * 8];
      s16x8 bu = *(const s16x8*)&B3lds[(wn + nf * 16 + lr) * BK + lq * 8];
#pragma unroll
      for (int mf = 0; mf < 4; ++mf) {
        accg[mf][nf] = __builtin_amdgcn_mfma_f32_16x16x32_bf16(af[mf], bg, accg[mf][nf], 0, 0, 0);
        accu[mf][nf] = __builtin_amdgcn_mfma_f32_16x16x32_bf16(af[mf], bu, accu[mf][nf], 0, 0, 0);
      }
    }
  }

  // epilogue: bias + oai-swiglu, store h (bf16)
#pragma unroll
  for (int nf = 0; nf < 4; ++nf) {
    const int col = n0 + wn + nf * 16 + lr;
    const float bg = b1g[e * FDIM + col];
    const float bu = b3g[e * FDIM + col];
#pragma unroll
    for (int mf = 0; mf < 4; ++mf) {
#pragma unroll
      for (int r = 0; r < 4; ++r) {
        const int row = wm + mf * 16 + lq * 4 + r;
        if (m0 + row < n_e) {
          float gate = accg[mf][nf][r] + bg;
          float up = accu[mf][nf][r] + bu;
          gate = fminf(gate, FLIMIT);
          up = fminf(fmaxf(up, -FLIMIT), FLIMIT);
          const float glu = gate / (1.f + __expf(-ALPHA_C * gate));
          const float hv = (up + 1.f) * glu;
          h[(size_t)rowtok[row] * FDIM + col] = f2bf(hv);
        }
      }
    }
  }
}

// ---------------- GEMM2: out += w_slot * (Hg@w2 + b2), scatter via atomicAdd ----------------
__global__ __launch_bounds__(256, 2) void gemm2_kernel(
    const short* __restrict__ h, const float* __restrict__ w2g,
    const float* __restrict__ b2g, const int* __restrict__ counts,
    const int* __restrict__ toklist, const float* __restrict__ wlist,
    float* __restrict__ out) {
  const int e = blockIdx.z;
  const int n_e = counts[e];
  const int m0 = blockIdx.x * BM;
  if (m0 >= n_e) return;
  const int n0 = blockIdx.y * BN;  // D columns
  const float* w2 = w2g + (size_t)e * FDIM * DDIM;

  __shared__ short Alds[BM * BK];
  __shared__ short Blds[BN * BK];  // [n][k]
  __shared__ int rowtok[BM];
  __shared__ float roww[BM];

  const int tid = threadIdx.x;
  if (tid < BM) {
    int r = m0 + tid;
    if (r >= n_e) r = n_e - 1;
    rowtok[tid] = toklist[e * T_TOK + r];
    roww[tid] = wlist[e * T_TOK + r];
  }
  __syncthreads();

  const int arow0 = tid >> 2;
  const int achk = tid & 3;
  const short* aptr0 = h + (size_t)rowtok[arow0] * FDIM + achk * 8;
  const short* aptr1 = h + (size_t)rowtok[arow0 + 64] * FDIM + achk * 8;

  const int bn = tid & 127;
  const int bkh = (tid >> 7) * 8;

  const int wave = tid >> 6;
  const int lane = tid & 63;
  const int wm = (wave >> 1) * 64;
  const int wn = (wave & 1) * 64;
  const int lr = lane & 15;
  const int lq = lane >> 4;

  f32x4 acc[4][4];
  const f32x4 zero = {0.f, 0.f, 0.f, 0.f};
#pragma unroll
  for (int i = 0; i < 4; ++i)
#pragma unroll
    for (int j = 0; j < 4; ++j) acc[i][j] = zero;

  for (int kt = 0; kt < FDIM / BK; ++kt) {
    __syncthreads();
    {
      u32x4 va0 = *(const u32x4*)(aptr0 + kt * BK);
      u32x4 va1 = *(const u32x4*)(aptr1 + kt * BK);
      *(u32x4*)&Alds[arow0 * BK + achk * 8] = va0;
      *(u32x4*)&Alds[(arow0 + 64) * BK + achk * 8] = va1;
    }
#pragma unroll
    for (int c = 0; c < 2; ++c) {
      const int k0 = bkh + c * 16;
      const float* s = w2 + (size_t)(kt * BK + k0) * DDIM + (n0 + bn);
      s16x8 v;
#pragma unroll
      for (int j = 0; j < 8; ++j) v[j] = f2bf(s[(size_t)j * DDIM]);
      *(s16x8*)&Blds[bn * BK + k0] = v;
    }
    __syncthreads();
    s16x8 af[4];
#pragma unroll
    for (int mf = 0; mf < 4; ++mf)
      af[mf] = *(const s16x8*)&Alds[(wm + mf * 16 + lr) * BK + lq * 8];
#pragma unroll
    for (int nf = 0; nf < 4; ++nf) {
      s16x8 bf = *(const s16x8*)&Blds[(wn + nf * 16 + lr) * BK + lq * 8];
#pragma unroll
      for (int mf = 0; mf < 4; ++mf)
        acc[mf][nf] = __builtin_amdgcn_mfma_f32_16x16x32_bf16(af[mf], bf, acc[mf][nf], 0, 0, 0);
    }
  }

#pragma unroll
  for (int nf = 0; nf < 4; ++nf) {
    const int col = n0 + wn + nf * 16 + lr;
    const float b2v = b2g[e * DDIM + col];
#pragma unroll
    for (int mf = 0; mf < 4; ++mf) {
#pragma unroll
      for (int r = 0; r < 4; ++r) {
        const int row = wm + mf * 16 + lq * 4 + r;
        if (m0 + row < n_e) {
          const float y = acc[mf][nf][r] + b2v;
          atomicAdd(&out[(size_t)(rowtok[row] >> 1) * DDIM + col], roww[row] * y);
        }
      }
    }
  }
}

extern "C" void kernel_launch(void* const* d_in, const int* in_sizes, int n_in,
                              void* d_out, int out_size, void* d_ws, size_t ws_size,
                              hipStream_t stream) {
  const float* x  = (const float*)d_in[0];
  const float* rw = (const float*)d_in[1];
  const float* rb = (const float*)d_in[2];
  const float* w1 = (const float*)d_in[3];
  const float* b1 = (const float*)d_in[4];
  const float* w3 = (const float*)d_in[5];
  const float* b3 = (const float*)d_in[6];
  const float* w2 = (const float*)d_in[7];
  const float* b2 = (const float*)d_in[8];
  float* out = (float*)d_out;

  char* ws = (char*)d_ws;
  int* counts = (int*)ws;                                   // 32 B
  int* toklist = (int*)(ws + 1024);                         // 128 KB
  float* wlist = (float*)(ws + 1024 + (size_t)NEXP * T_TOK * 4);
  short* xb = (short*)(ws + (1 << 20));                     // 16 MB
  short* h  = (short*)(ws + (1 << 20) + (size_t)T_TOK * DDIM * 2);  // 64 MB

  hipMemsetAsync(counts, 0, NEXP * sizeof(int), stream);
  hipMemsetAsync(out, 0, (size_t)out_size * sizeof(float), stream);

  router_kernel<<<dim3(T_TOK / 4), dim3(256), 0, stream>>>(x, rw, rb, xb, counts,
                                                           toklist, wlist);
  gemm1_kernel<<<dim3(T_TOK / BM, FDIM / BN, NEXP), dim3(256), 0, stream>>>(
      xb, w1, b1, w3, b3, counts, toklist, h);
  gemm2_kernel<<<dim3(T_TOK / BM, DDIM / BN, NEXP), dim3(256), 0, stream>>>(
      h, w2, b2, counts, toklist, wlist, out);
}